// Round 1
// baseline (360.094 us; speedup 1.0000x reference)
//
#include <hip/hip_runtime.h>

#define N_NODES 50000
#define N_EDGES 800000
#define D_FEAT 128
#define HEADS 8
#define HEAD_DIM 16

// ---------------- workspace layout (bytes) ----------------
static constexpr size_t OFF_H    = 0;                                   // [N,128] f32
static constexpr size_t OFF_ASRC = OFF_H    + (size_t)N_NODES * 128 * 4; // [N,8] f32
static constexpr size_t OFF_ADST = OFF_ASRC + (size_t)N_NODES * 8 * 4;   // [N,8] f32
static constexpr size_t OFF_CNT  = OFF_ADST + (size_t)N_NODES * 8 * 4;   // [N] i32
static constexpr size_t OFF_OFFS = OFF_CNT  + ((size_t)N_NODES * 4 + 255 & ~255ull); // [N+1] i32
static constexpr size_t OFF_RUN  = OFF_OFFS + (((size_t)(N_NODES + 1) * 4 + 255) & ~255ull); // [N] i32
static constexpr size_t OFF_CSR  = OFF_RUN  + ((size_t)N_NODES * 4 + 255 & ~255ull); // [E] i32

// ---------------- kernel A: h = x @ W (fp32, W in LDS) ----------------
// block = 256 threads, handles 32 node rows. W: 128x128 f32 in LDS (64KB),
// x tile 32x128 padded to stride 132 (16.9KB). 1 block/CU (81KB LDS) is fine
// for this short kernel.
__global__ __launch_bounds__(256) void k_gemm(const float* __restrict__ x,
                                              const float* __restrict__ W,
                                              float* __restrict__ h, int N) {
  __shared__ float4 Wl[128][32];
  __shared__ float  xl[32][132];
  const int tid = threadIdx.x;

  const float4* W4 = (const float4*)W;
#pragma unroll
  for (int i = 0; i < 16; ++i) {
    int idx = tid + i * 256;            // 0..4095
    ((float4*)Wl)[idx] = W4[idx];       // row-major match
  }
  const int r0 = blockIdx.x * 32;
  const float4* x4 = (const float4*)x;
#pragma unroll
  for (int i = 0; i < 4; ++i) {
    int idx = tid + i * 256;            // 0..1023
    int row = idx >> 5;
    int c4  = idx & 31;
    float4 v = make_float4(0.f, 0.f, 0.f, 0.f);
    if (r0 + row < N) v = x4[(size_t)(r0 + row) * 32 + c4];
    *(float4*)&xl[row][c4 * 4] = v;
  }
  __syncthreads();

  const int tcol = tid & 31;   // output col group (4 cols)
  const int trow = tid >> 5;   // node group (4 nodes)
  float4 acc[4];
#pragma unroll
  for (int i = 0; i < 4; ++i) acc[i] = make_float4(0.f, 0.f, 0.f, 0.f);

  for (int k4 = 0; k4 < 32; ++k4) {
    float4 w0 = Wl[4 * k4 + 0][tcol];
    float4 w1 = Wl[4 * k4 + 1][tcol];
    float4 w2 = Wl[4 * k4 + 2][tcol];
    float4 w3 = Wl[4 * k4 + 3][tcol];
#pragma unroll
    for (int i = 0; i < 4; ++i) {
      float4 xv = *(const float4*)&xl[trow * 4 + i][k4 * 4];
      acc[i].x = fmaf(w0.x, xv.x, acc[i].x); acc[i].x = fmaf(w1.x, xv.y, acc[i].x);
      acc[i].x = fmaf(w2.x, xv.z, acc[i].x); acc[i].x = fmaf(w3.x, xv.w, acc[i].x);
      acc[i].y = fmaf(w0.y, xv.x, acc[i].y); acc[i].y = fmaf(w1.y, xv.y, acc[i].y);
      acc[i].y = fmaf(w2.y, xv.z, acc[i].y); acc[i].y = fmaf(w3.y, xv.w, acc[i].y);
      acc[i].z = fmaf(w0.z, xv.x, acc[i].z); acc[i].z = fmaf(w1.z, xv.y, acc[i].z);
      acc[i].z = fmaf(w2.z, xv.z, acc[i].z); acc[i].z = fmaf(w3.z, xv.w, acc[i].z);
      acc[i].w = fmaf(w0.w, xv.x, acc[i].w); acc[i].w = fmaf(w1.w, xv.y, acc[i].w);
      acc[i].w = fmaf(w2.w, xv.z, acc[i].w); acc[i].w = fmaf(w3.w, xv.w, acc[i].w);
    }
  }
#pragma unroll
  for (int i = 0; i < 4; ++i) {
    int row = r0 + trow * 4 + i;
    if (row < N) ((float4*)h)[(size_t)row * 32 + tcol] = acc[i];
  }
}

// ---------------- kernel A2: per-(node,head) attention logits ----------------
__global__ __launch_bounds__(256) void k_att(const float* __restrict__ h,
                                             const float* __restrict__ att_src,
                                             const float* __restrict__ att_dst,
                                             float* __restrict__ a_src,
                                             float* __restrict__ a_dst, int NH) {
  int t = blockIdx.x * 256 + threadIdx.x;
  if (t >= NH) return;
  int hd = t & 7;
  const float4* h4  = (const float4*)h;
  const float4* as4 = (const float4*)att_src;
  const float4* ad4 = (const float4*)att_dst;
  float s = 0.f, d = 0.f;
#pragma unroll
  for (int i = 0; i < 4; ++i) {
    float4 hv = h4[(size_t)t * 4 + i];
    float4 av = as4[hd * 4 + i];
    float4 dv = ad4[hd * 4 + i];
    s += hv.x * av.x + hv.y * av.y + hv.z * av.z + hv.w * av.w;
    d += hv.x * dv.x + hv.y * dv.y + hv.z * dv.z + hv.w * dv.w;
  }
  a_src[t] = s;
  a_dst[t] = d;
}

// ---------------- CSR build ----------------
__global__ void k_zero(int* __restrict__ p, int n) {
  int t = blockIdx.x * blockDim.x + threadIdx.x;
  if (t < n) p[t] = 0;
}

__global__ void k_count(const int* __restrict__ dst, int* __restrict__ cnt, int E) {
  for (int e = blockIdx.x * blockDim.x + threadIdx.x; e < E; e += gridDim.x * blockDim.x)
    atomicAdd(&cnt[dst[e]], 1);
}

__global__ __launch_bounds__(1024) void k_scan(const int* __restrict__ cnt,
                                               int* __restrict__ offs,
                                               int* __restrict__ run, int N) {
  __shared__ int s[1024];
  const int t = threadIdx.x;
  const int chunk = (N + 1023) >> 10;
  const int b = t * chunk;
  const int e = min(b + chunk, N);
  int sum = 0;
  for (int i = b; i < e; ++i) sum += cnt[i];
  s[t] = sum;
  __syncthreads();
  for (int off = 1; off < 1024; off <<= 1) {
    int v = (t >= off) ? s[t - off] : 0;
    __syncthreads();
    s[t] += v;
    __syncthreads();
  }
  int running = (t == 0) ? 0 : s[t - 1];
  for (int i = b; i < e; ++i) {
    offs[i] = running;
    run[i] = running;
    running += cnt[i];
  }
  if (b < N && e == N) offs[N] = running;
}

__global__ void k_scatter(const int* __restrict__ src, const int* __restrict__ dst,
                          int* __restrict__ run, int* __restrict__ csr, int E) {
  for (int e = blockIdx.x * blockDim.x + threadIdx.x; e < E; e += gridDim.x * blockDim.x) {
    int p = atomicAdd(&run[dst[e]], 1);
    csr[p] = src[e];
  }
}

// ---------------- kernel C: gather + softmax-normalized aggregate + residual + LN ----------------
// one wave per dst node; lane owns features {2*lane, 2*lane+1}; head = lane>>3.
// alpha normalization factors out: out = (sum p*h) / (sum p).  No segment_max
// needed (logits are O(1); exp cannot overflow) -- mathematically identical.
__global__ __launch_bounds__(256) void k_gat(const float* __restrict__ h,
                                             const float* __restrict__ a_src,
                                             const float* __restrict__ a_dst,
                                             const int* __restrict__ offs,
                                             const int* __restrict__ csr,
                                             const float* __restrict__ x,
                                             const float* __restrict__ bias,
                                             const float* __restrict__ gamma,
                                             const float* __restrict__ beta,
                                             float* __restrict__ out, int N) {
  const int wid = threadIdx.x >> 6;
  const int lane = threadIdx.x & 63;
  const int n = blockIdx.x * 4 + wid;
  if (n >= N) return;
  const int hd = lane >> 3;
  const float adst = a_dst[n * 8 + hd];
  const int e0 = offs[n], e1 = offs[n + 1];
  const float2* h2 = (const float2*)h;

  float acc0 = 0.f, acc1 = 0.f, den = 0.f;
  for (int e = e0; e < e1; ++e) {
    int s = csr[e];
    float a = a_src[s * 8 + hd] + adst;
    a = a > 0.f ? a : 0.2f * a;           // LeakyReLU(0.2)
    float p = __expf(a);
    float2 hv = h2[(size_t)s * 64 + lane];
    acc0 = fmaf(p, hv.x, acc0);
    acc1 = fmaf(p, hv.y, acc1);
    den += p;
  }
  float r = 1.0f / (den + 1e-16f);
  float2 bv = ((const float2*)bias)[lane];
  float2 xv = ((const float2*)x)[(size_t)n * 64 + lane];
  float o0 = fmaf(acc0, r, bv.x + xv.x);
  float o1 = fmaf(acc1, r, bv.y + xv.y);

  // wave-wide LayerNorm over 128 features
  float s1 = o0 + o1;
  float s2 = o0 * o0 + o1 * o1;
#pragma unroll
  for (int off = 32; off > 0; off >>= 1) {
    s1 += __shfl_xor(s1, off);
    s2 += __shfl_xor(s2, off);
  }
  float mean = s1 * (1.0f / 128.0f);
  float var = s2 * (1.0f / 128.0f) - mean * mean;
  var = var < 0.f ? 0.f : var;
  float rstd = rsqrtf(var + 1e-5f);
  float2 gv = ((const float2*)gamma)[lane];
  float2 bt = ((const float2*)beta)[lane];
  float2 ov;
  ov.x = (o0 - mean) * rstd * gv.x + bt.x;
  ov.y = (o1 - mean) * rstd * gv.y + bt.y;
  ((float2*)out)[(size_t)n * 64 + lane] = ov;
}

// ---------------- launch ----------------
extern "C" void kernel_launch(void* const* d_in, const int* in_sizes, int n_in,
                              void* d_out, int out_size, void* d_ws, size_t ws_size,
                              hipStream_t stream) {
  const float* x       = (const float*)d_in[0];
  const int*   ei      = (const int*)d_in[1];
  const float* W       = (const float*)d_in[2];
  const float* att_src = (const float*)d_in[3];
  const float* att_dst = (const float*)d_in[4];
  const float* bias    = (const float*)d_in[5];
  const float* gamma   = (const float*)d_in[6];
  const float* beta    = (const float*)d_in[7];
  float* out = (float*)d_out;

  char* ws = (char*)d_ws;
  float* h     = (float*)(ws + OFF_H);
  float* a_src = (float*)(ws + OFF_ASRC);
  float* a_dst = (float*)(ws + OFF_ADST);
  int* cnt  = (int*)(ws + OFF_CNT);
  int* offs = (int*)(ws + OFF_OFFS);
  int* run  = (int*)(ws + OFF_RUN);
  int* csr  = (int*)(ws + OFF_CSR);

  const int* srcIdx = ei;
  const int* dstIdx = ei + N_EDGES;

  k_gemm<<<(N_NODES + 31) / 32, 256, 0, stream>>>(x, W, h, N_NODES);
  k_att<<<(N_NODES * 8 + 255) / 256, 256, 0, stream>>>(h, att_src, att_dst, a_src, a_dst, N_NODES * 8);
  k_zero<<<(N_NODES + 255) / 256, 256, 0, stream>>>(cnt, N_NODES);
  k_count<<<1024, 256, 0, stream>>>(dstIdx, cnt, N_EDGES);
  k_scan<<<1, 1024, 0, stream>>>(cnt, offs, run, N_NODES);
  k_scatter<<<1024, 256, 0, stream>>>(srcIdx, dstIdx, run, csr, N_EDGES);
  k_gat<<<(N_NODES + 3) / 4, 256, 0, stream>>>(h, a_src, a_dst, offs, csr, x, bias, gamma, beta, out, N_NODES);
}

// Round 2
// 259.232 us; speedup vs baseline: 1.3891x; 1.3891x over previous
//
#include <hip/hip_runtime.h>

#define N_NODES 50000
#define N_EDGES 800000
#define D_FEAT 128
#define HEADS 8
#define HEAD_DIM 16

#define SCAN_BLK 1024
#define SCAN_NB ((N_NODES + SCAN_BLK - 1) / SCAN_BLK)   // 49

// ---------------- workspace layout (bytes) ----------------
static constexpr size_t OFF_H    = 0;                                   // [N,128] f32
static constexpr size_t OFF_ASRC = OFF_H    + (size_t)N_NODES * 128 * 4; // [N,8] f32
static constexpr size_t OFF_ADST = OFF_ASRC + (size_t)N_NODES * 8 * 4;   // [N,8] f32
static constexpr size_t OFF_CNT  = OFF_ADST + (size_t)N_NODES * 8 * 4;   // [N] i32
static constexpr size_t OFF_OFFS = OFF_CNT  + ((size_t)N_NODES * 4 + 255 & ~255ull); // [N+1] i32
static constexpr size_t OFF_RUN  = OFF_OFFS + (((size_t)(N_NODES + 1) * 4 + 255) & ~255ull); // [N] i32
static constexpr size_t OFF_CSR  = OFF_RUN  + ((size_t)N_NODES * 4 + 255 & ~255ull); // [E] i32
static constexpr size_t OFF_BSUM = OFF_CSR  + (((size_t)N_EDGES * 4 + 255) & ~255ull); // [49] i32

// ---------------- kernel A: h = x @ W (fp32, W in LDS) ----------------
__global__ __launch_bounds__(256) void k_gemm(const float* __restrict__ x,
                                              const float* __restrict__ W,
                                              float* __restrict__ h, int N) {
  __shared__ float4 Wl[128][32];
  __shared__ float  xl[32][132];
  const int tid = threadIdx.x;

  const float4* W4 = (const float4*)W;
#pragma unroll
  for (int i = 0; i < 16; ++i) {
    int idx = tid + i * 256;            // 0..4095
    ((float4*)Wl)[idx] = W4[idx];       // row-major match
  }
  const int r0 = blockIdx.x * 32;
  const float4* x4 = (const float4*)x;
#pragma unroll
  for (int i = 0; i < 4; ++i) {
    int idx = tid + i * 256;            // 0..1023
    int row = idx >> 5;
    int c4  = idx & 31;
    float4 v = make_float4(0.f, 0.f, 0.f, 0.f);
    if (r0 + row < N) v = x4[(size_t)(r0 + row) * 32 + c4];
    *(float4*)&xl[row][c4 * 4] = v;
  }
  __syncthreads();

  const int tcol = tid & 31;   // output col group (4 cols)
  const int trow = tid >> 5;   // node group (4 nodes)
  float4 acc[4];
#pragma unroll
  for (int i = 0; i < 4; ++i) acc[i] = make_float4(0.f, 0.f, 0.f, 0.f);

  for (int k4 = 0; k4 < 32; ++k4) {
    float4 w0 = Wl[4 * k4 + 0][tcol];
    float4 w1 = Wl[4 * k4 + 1][tcol];
    float4 w2 = Wl[4 * k4 + 2][tcol];
    float4 w3 = Wl[4 * k4 + 3][tcol];
#pragma unroll
    for (int i = 0; i < 4; ++i) {
      float4 xv = *(const float4*)&xl[trow * 4 + i][k4 * 4];
      acc[i].x = fmaf(w0.x, xv.x, acc[i].x); acc[i].x = fmaf(w1.x, xv.y, acc[i].x);
      acc[i].x = fmaf(w2.x, xv.z, acc[i].x); acc[i].x = fmaf(w3.x, xv.w, acc[i].x);
      acc[i].y = fmaf(w0.y, xv.x, acc[i].y); acc[i].y = fmaf(w1.y, xv.y, acc[i].y);
      acc[i].y = fmaf(w2.y, xv.z, acc[i].y); acc[i].y = fmaf(w3.y, xv.w, acc[i].y);
      acc[i].z = fmaf(w0.z, xv.x, acc[i].z); acc[i].z = fmaf(w1.z, xv.y, acc[i].z);
      acc[i].z = fmaf(w2.z, xv.z, acc[i].z); acc[i].z = fmaf(w3.z, xv.w, acc[i].z);
      acc[i].w = fmaf(w0.w, xv.x, acc[i].w); acc[i].w = fmaf(w1.w, xv.y, acc[i].w);
      acc[i].w = fmaf(w2.w, xv.z, acc[i].w); acc[i].w = fmaf(w3.w, xv.w, acc[i].w);
    }
  }
#pragma unroll
  for (int i = 0; i < 4; ++i) {
    int row = r0 + trow * 4 + i;
    if (row < N) ((float4*)h)[(size_t)row * 32 + tcol] = acc[i];
  }
}

// ---------------- kernel A2: per-(node,head) attention logits ----------------
__global__ __launch_bounds__(256) void k_att(const float* __restrict__ h,
                                             const float* __restrict__ att_src,
                                             const float* __restrict__ att_dst,
                                             float* __restrict__ a_src,
                                             float* __restrict__ a_dst, int NH) {
  int t = blockIdx.x * 256 + threadIdx.x;
  if (t >= NH) return;
  int hd = t & 7;
  const float4* h4  = (const float4*)h;
  const float4* as4 = (const float4*)att_src;
  const float4* ad4 = (const float4*)att_dst;
  float s = 0.f, d = 0.f;
#pragma unroll
  for (int i = 0; i < 4; ++i) {
    float4 hv = h4[(size_t)t * 4 + i];
    float4 av = as4[hd * 4 + i];
    float4 dv = ad4[hd * 4 + i];
    s += hv.x * av.x + hv.y * av.y + hv.z * av.z + hv.w * av.w;
    d += hv.x * dv.x + hv.y * dv.y + hv.z * dv.z + hv.w * dv.w;
  }
  a_src[t] = s;
  a_dst[t] = d;
}

// ---------------- CSR build ----------------
__global__ void k_zero(int* __restrict__ p, int n) {
  int t = blockIdx.x * blockDim.x + threadIdx.x;
  if (t < n) p[t] = 0;
}

__global__ void k_count(const int* __restrict__ dst, int* __restrict__ cnt, int E) {
  for (int e = blockIdx.x * blockDim.x + threadIdx.x; e < E; e += gridDim.x * blockDim.x)
    atomicAdd(&cnt[dst[e]], 1);
}

// --- 3-level hierarchical exclusive scan of cnt[0..N) -> offs/run, bsum ---
__global__ __launch_bounds__(SCAN_BLK) void k_scan1(const int* __restrict__ cnt,
                                                    int* __restrict__ offs,
                                                    int* __restrict__ run,
                                                    int* __restrict__ bsum, int N) {
  __shared__ int s[SCAN_BLK];
  const int t = threadIdx.x;
  const int gid = blockIdx.x * SCAN_BLK + t;
  int v = (gid < N) ? cnt[gid] : 0;
  s[t] = v;
  __syncthreads();
#pragma unroll
  for (int off = 1; off < SCAN_BLK; off <<= 1) {
    int u = (t >= off) ? s[t - off] : 0;
    __syncthreads();
    s[t] += u;
    __syncthreads();
  }
  int excl = s[t] - v;
  if (gid < N) { offs[gid] = excl; run[gid] = excl; }
  if (t == SCAN_BLK - 1) bsum[blockIdx.x] = s[t];
}

__global__ void k_scan2(int* __restrict__ bsum, int nb) {
  int lane = threadIdx.x;          // single wave of 64
  int v = (lane < nb) ? bsum[lane] : 0;
#pragma unroll
  for (int off = 1; off < 64; off <<= 1) {
    int u = __shfl_up(v, off);
    if (lane >= off) v += u;
  }
  if (lane < nb) bsum[lane] = v;   // inclusive block sums
}

__global__ __launch_bounds__(SCAN_BLK) void k_scan3(const int* __restrict__ bsum,
                                                    int* __restrict__ offs,
                                                    int* __restrict__ run, int N, int nb) {
  const int gid = blockIdx.x * SCAN_BLK + threadIdx.x;
  const int base = (blockIdx.x > 0) ? bsum[blockIdx.x - 1] : 0;
  if (gid < N) { offs[gid] += base; run[gid] += base; }
  if (gid == 0) offs[N] = bsum[nb - 1];   // total edge count
}

__global__ void k_scatter(const int* __restrict__ src, const int* __restrict__ dst,
                          int* __restrict__ run, int* __restrict__ csr, int E) {
  for (int e = blockIdx.x * blockDim.x + threadIdx.x; e < E; e += gridDim.x * blockDim.x) {
    int p = atomicAdd(&run[dst[e]], 1);
    csr[p] = src[e];
  }
}

// ---------------- kernel C: gather + softmax aggregate + residual + LN ----------------
__global__ __launch_bounds__(256) void k_gat(const float* __restrict__ h,
                                             const float* __restrict__ a_src,
                                             const float* __restrict__ a_dst,
                                             const int* __restrict__ offs,
                                             const int* __restrict__ csr,
                                             const float* __restrict__ x,
                                             const float* __restrict__ bias,
                                             const float* __restrict__ gamma,
                                             const float* __restrict__ beta,
                                             float* __restrict__ out, int N) {
  const int wid = threadIdx.x >> 6;
  const int lane = threadIdx.x & 63;
  const int n = blockIdx.x * 4 + wid;
  if (n >= N) return;
  const int hd = lane >> 3;
  const float adst = a_dst[n * 8 + hd];
  const int e0 = offs[n], e1 = offs[n + 1];
  const float2* h2 = (const float2*)h;

  float acc0 = 0.f, acc1 = 0.f, den = 0.f;
  for (int e = e0; e < e1; ++e) {
    int s = csr[e];
    float a = a_src[s * 8 + hd] + adst;
    a = a > 0.f ? a : 0.2f * a;           // LeakyReLU(0.2)
    float p = __expf(a);
    float2 hv = h2[(size_t)s * 64 + lane];
    acc0 = fmaf(p, hv.x, acc0);
    acc1 = fmaf(p, hv.y, acc1);
    den += p;
  }
  float r = 1.0f / (den + 1e-16f);
  float2 bv = ((const float2*)bias)[lane];
  float2 xv = ((const float2*)x)[(size_t)n * 64 + lane];
  float o0 = fmaf(acc0, r, bv.x + xv.x);
  float o1 = fmaf(acc1, r, bv.y + xv.y);

  float s1 = o0 + o1;
  float s2 = o0 * o0 + o1 * o1;
#pragma unroll
  for (int off = 32; off > 0; off >>= 1) {
    s1 += __shfl_xor(s1, off);
    s2 += __shfl_xor(s2, off);
  }
  float mean = s1 * (1.0f / 128.0f);
  float var = s2 * (1.0f / 128.0f) - mean * mean;
  var = var < 0.f ? 0.f : var;
  float rstd = rsqrtf(var + 1e-5f);
  float2 gv = ((const float2*)gamma)[lane];
  float2 bt = ((const float2*)beta)[lane];
  float2 ov;
  ov.x = (o0 - mean) * rstd * gv.x + bt.x;
  ov.y = (o1 - mean) * rstd * gv.y + bt.y;
  ((float2*)out)[(size_t)n * 64 + lane] = ov;
}

// ---------------- launch ----------------
extern "C" void kernel_launch(void* const* d_in, const int* in_sizes, int n_in,
                              void* d_out, int out_size, void* d_ws, size_t ws_size,
                              hipStream_t stream) {
  const float* x       = (const float*)d_in[0];
  const int*   ei      = (const int*)d_in[1];
  const float* W       = (const float*)d_in[2];
  const float* att_src = (const float*)d_in[3];
  const float* att_dst = (const float*)d_in[4];
  const float* bias    = (const float*)d_in[5];
  const float* gamma   = (const float*)d_in[6];
  const float* beta    = (const float*)d_in[7];
  float* out = (float*)d_out;

  char* ws = (char*)d_ws;
  float* h     = (float*)(ws + OFF_H);
  float* a_src = (float*)(ws + OFF_ASRC);
  float* a_dst = (float*)(ws + OFF_ADST);
  int* cnt  = (int*)(ws + OFF_CNT);
  int* offs = (int*)(ws + OFF_OFFS);
  int* run  = (int*)(ws + OFF_RUN);
  int* csr  = (int*)(ws + OFF_CSR);
  int* bsum = (int*)(ws + OFF_BSUM);

  const int* srcIdx = ei;
  const int* dstIdx = ei + N_EDGES;

  k_gemm<<<(N_NODES + 31) / 32, 256, 0, stream>>>(x, W, h, N_NODES);
  k_att<<<(N_NODES * 8 + 255) / 256, 256, 0, stream>>>(h, att_src, att_dst, a_src, a_dst, N_NODES * 8);
  k_zero<<<(N_NODES + 255) / 256, 256, 0, stream>>>(cnt, N_NODES);
  k_count<<<1024, 256, 0, stream>>>(dstIdx, cnt, N_EDGES);
  k_scan1<<<SCAN_NB, SCAN_BLK, 0, stream>>>(cnt, offs, run, bsum, N_NODES);
  k_scan2<<<1, 64, 0, stream>>>(bsum, SCAN_NB);
  k_scan3<<<SCAN_NB, SCAN_BLK, 0, stream>>>(bsum, offs, run, N_NODES, SCAN_NB);
  k_scatter<<<1024, 256, 0, stream>>>(srcIdx, dstIdx, run, csr, N_EDGES);
  k_gat<<<(N_NODES + 3) / 4, 256, 0, stream>>>(h, a_src, a_dst, offs, csr, x, bias, gamma, beta, out, N_NODES);
}

// Round 3
// 173.420 us; speedup vs baseline: 2.0764x; 1.4948x over previous
//
#include <hip/hip_runtime.h>

#define N_NODES 50000
#define N_EDGES 800000
#define D_FEAT 128
#define HEADS 8
#define HEAD_DIM 16

#define SCAN_BLK 1024
#define SCAN_NB ((N_NODES + SCAN_BLK - 1) / SCAN_BLK)   // 49

typedef __attribute__((ext_vector_type(8))) short bf16x8;
typedef __attribute__((ext_vector_type(4))) float f32x4;

static __device__ __forceinline__ ushort f2bf(float f) {
  uint u = __float_as_uint(f);
  u += 0x7fffu + ((u >> 16) & 1u);    // RNE
  return (ushort)(u >> 16);
}
static __device__ __forceinline__ float bf2f_lo(uint u) { return __uint_as_float(u << 16); }
static __device__ __forceinline__ float bf2f_hi(uint u) { return __uint_as_float(u & 0xffff0000u); }

static constexpr size_t alignup(size_t v) { return (v + 255) & ~255ull; }
// ---------------- workspace layout (bytes) ----------------
static constexpr size_t OFF_HB   = 0;                                        // [N,128] bf16
static constexpr size_t OFF_ASRC = alignup(OFF_HB + (size_t)N_NODES * 128 * 2); // [N,8] f32
static constexpr size_t OFF_ADST = alignup(OFF_ASRC + (size_t)N_NODES * 8 * 4); // [N,8] f32
static constexpr size_t OFF_CNT  = alignup(OFF_ADST + (size_t)N_NODES * 8 * 4); // [N] i32
static constexpr size_t OFF_OFFS = alignup(OFF_CNT + (size_t)N_NODES * 4);      // [N+1] i32
static constexpr size_t OFF_RUN  = alignup(OFF_OFFS + (size_t)(N_NODES + 1) * 4); // [N] i32
static constexpr size_t OFF_CSR  = alignup(OFF_RUN + (size_t)N_NODES * 4);      // [E] i32
static constexpr size_t OFF_BSUM = alignup(OFF_CSR + (size_t)N_EDGES * 4);      // [49] i32
static constexpr size_t OFF_WT   = alignup(OFF_BSUM + 64 * 4);                  // [128*128] bf16 swizzled

// ---------------- prep: Wt bf16, transposed [n][k], XOR-swizzled ----------------
__global__ __launch_bounds__(256) void k_prep(const float* __restrict__ W,
                                              char* __restrict__ Wt) {
  int t = blockIdx.x * 256 + threadIdx.x;   // 0..16383
  int n = t >> 7, k = t & 127;
  int off = (n * 256 + k * 2) ^ ((n & 7) << 4);
  *(ushort*)(Wt + off) = f2bf(W[k * 128 + n]);
}

// ---------------- MFMA GEMM: h_bf16 = bf16(x) @ W ----------------
// block: 64 rows, 4 waves; wave: 16 rows x 128 cols, 8 acc tiles, K-loop x4.
__global__ __launch_bounds__(256) void k_gemm2(const float* __restrict__ x,
                                               const char* __restrict__ Wt,
                                               ushort* __restrict__ hb, int N) {
  __shared__ ushort Wl[16384];              // 32KB, swizzled [n][k] bf16
  const int tid = threadIdx.x;
  const uint4* Wg4 = (const uint4*)Wt;
  uint4* Wl4 = (uint4*)Wl;
#pragma unroll
  for (int i = 0; i < 8; ++i) Wl4[tid + i * 256] = Wg4[tid + i * 256];
  __syncthreads();

  const int w = tid >> 6, l = tid & 63;
  const int R = blockIdx.x * 64 + w * 16;
  const int m = l & 15, kg = l >> 4;
  const char* Wlb = (const char*)Wl;

  f32x4 acc[8];
#pragma unroll
  for (int j = 0; j < 8; ++j) acc[j] = (f32x4){0.f, 0.f, 0.f, 0.f};

  const int row = R + m;
  const bool valid = row < N;
  const float4* xr = (const float4*)(x + (size_t)(valid ? row : 0) * 128);

#pragma unroll
  for (int kt = 0; kt < 4; ++kt) {
    const int k0 = kt * 32 + kg * 8;
    float4 xa = valid ? xr[k0 >> 2] : make_float4(0.f, 0.f, 0.f, 0.f);
    float4 xb = valid ? xr[(k0 >> 2) + 1] : make_float4(0.f, 0.f, 0.f, 0.f);
    bf16x8 a;
    a[0] = (short)f2bf(xa.x); a[1] = (short)f2bf(xa.y);
    a[2] = (short)f2bf(xa.z); a[3] = (short)f2bf(xa.w);
    a[4] = (short)f2bf(xb.x); a[5] = (short)f2bf(xb.y);
    a[6] = (short)f2bf(xb.z); a[7] = (short)f2bf(xb.w);
#pragma unroll
    for (int j = 0; j < 8; ++j) {
      int n = j * 16 + m;
      int off = (n * 256 + k0 * 2) ^ ((n & 7) << 4);
      bf16x8 b = *(const bf16x8*)(Wlb + off);
      acc[j] = __builtin_amdgcn_mfma_f32_16x16x32_bf16(a, b, acc[j], 0, 0, 0);
    }
  }
  // C layout: col = lane&15, row = (lane>>4)*4 + reg
#pragma unroll
  for (int j = 0; j < 8; ++j) {
    int col = j * 16 + m;
#pragma unroll
    for (int r = 0; r < 4; ++r) {
      int rr = R + kg * 4 + r;
      if (rr < N) hb[(size_t)rr * 128 + col] = f2bf(acc[j][r]);
    }
  }
}

// ---------------- per-(node,head) attention logits (bf16 h) ----------------
__global__ __launch_bounds__(256) void k_att(const ushort* __restrict__ hb,
                                             const float* __restrict__ att_src,
                                             const float* __restrict__ att_dst,
                                             float* __restrict__ a_src,
                                             float* __restrict__ a_dst, int NH) {
  int t = blockIdx.x * 256 + threadIdx.x;
  if (t >= NH) return;
  int hd = t & 7;
  const uint* hu = (const uint*)hb;         // 2 bf16 per uint; 8 uints per (node,head)
  float s = 0.f, d = 0.f;
#pragma unroll
  for (int i = 0; i < 8; ++i) {
    uint u = hu[(size_t)t * 8 + i];
    float f0 = bf2f_lo(u), f1 = bf2f_hi(u);
    s += f0 * att_src[hd * 16 + 2 * i] + f1 * att_src[hd * 16 + 2 * i + 1];
    d += f0 * att_dst[hd * 16 + 2 * i] + f1 * att_dst[hd * 16 + 2 * i + 1];
  }
  a_src[t] = s;
  a_dst[t] = d;
}

// ---------------- CSR build ----------------
__global__ void k_zero(int* __restrict__ p, int n) {
  int t = blockIdx.x * blockDim.x + threadIdx.x;
  if (t < n) p[t] = 0;
}

__global__ void k_count(const int* __restrict__ dst, int* __restrict__ cnt, int E) {
  for (int e = blockIdx.x * blockDim.x + threadIdx.x; e < E; e += gridDim.x * blockDim.x)
    atomicAdd(&cnt[dst[e]], 1);
}

__global__ __launch_bounds__(SCAN_BLK) void k_scan1(const int* __restrict__ cnt,
                                                    int* __restrict__ offs,
                                                    int* __restrict__ run,
                                                    int* __restrict__ bsum, int N) {
  __shared__ int s[SCAN_BLK];
  const int t = threadIdx.x;
  const int gid = blockIdx.x * SCAN_BLK + t;
  int v = (gid < N) ? cnt[gid] : 0;
  s[t] = v;
  __syncthreads();
#pragma unroll
  for (int off = 1; off < SCAN_BLK; off <<= 1) {
    int u = (t >= off) ? s[t - off] : 0;
    __syncthreads();
    s[t] += u;
    __syncthreads();
  }
  int excl = s[t] - v;
  if (gid < N) { offs[gid] = excl; run[gid] = excl; }
  if (t == SCAN_BLK - 1) bsum[blockIdx.x] = s[t];
}

__global__ void k_scan2(int* __restrict__ bsum, int nb) {
  int lane = threadIdx.x;
  int v = (lane < nb) ? bsum[lane] : 0;
#pragma unroll
  for (int off = 1; off < 64; off <<= 1) {
    int u = __shfl_up(v, off);
    if (lane >= off) v += u;
  }
  if (lane < nb) bsum[lane] = v;
}

__global__ __launch_bounds__(SCAN_BLK) void k_scan3(const int* __restrict__ bsum,
                                                    int* __restrict__ offs,
                                                    int* __restrict__ run, int N, int nb) {
  const int gid = blockIdx.x * SCAN_BLK + threadIdx.x;
  const int base = (blockIdx.x > 0) ? bsum[blockIdx.x - 1] : 0;
  if (gid < N) { offs[gid] += base; run[gid] += base; }
  if (gid == 0) offs[N] = bsum[nb - 1];
}

__global__ void k_scatter(const int* __restrict__ src, const int* __restrict__ dst,
                          int* __restrict__ run, int* __restrict__ csr, int E) {
  for (int e = blockIdx.x * blockDim.x + threadIdx.x; e < E; e += gridDim.x * blockDim.x) {
    int p = atomicAdd(&run[dst[e]], 1);
    csr[p] = src[e];
  }
}

// ---------------- gather + softmax aggregate + residual + LN ----------------
// one wave per dst node; lane owns features {2*lane, 2*lane+1} (one uint of h);
// head = lane>>3. alpha normalization factors out: out = (sum p*h)/(sum p).
__global__ __launch_bounds__(256) void k_gat(const ushort* __restrict__ hb,
                                             const float* __restrict__ a_src,
                                             const float* __restrict__ a_dst,
                                             const int* __restrict__ offs,
                                             const int* __restrict__ csr,
                                             const float* __restrict__ x,
                                             const float* __restrict__ bias,
                                             const float* __restrict__ gamma,
                                             const float* __restrict__ beta,
                                             float* __restrict__ out, int N) {
  const int wid = threadIdx.x >> 6;
  const int lane = threadIdx.x & 63;
  const int n = blockIdx.x * 4 + wid;
  if (n >= N) return;
  const int hd = lane >> 3;
  const float adst = a_dst[n * 8 + hd];
  const int e0 = offs[n], e1 = offs[n + 1];
  const uint* hu = (const uint*)hb;

  float acc0 = 0.f, acc1 = 0.f, den = 0.f;
  int e = e0;
  for (; e + 4 <= e1; e += 4) {
    int s0 = csr[e], s1 = csr[e + 1], s2 = csr[e + 2], s3 = csr[e + 3];
    float A0 = a_src[s0 * 8 + hd], A1 = a_src[s1 * 8 + hd];
    float A2 = a_src[s2 * 8 + hd], A3 = a_src[s3 * 8 + hd];
    uint u0 = hu[(size_t)s0 * 64 + lane], u1 = hu[(size_t)s1 * 64 + lane];
    uint u2 = hu[(size_t)s2 * 64 + lane], u3 = hu[(size_t)s3 * 64 + lane];
    float a0 = A0 + adst; a0 = a0 > 0.f ? a0 : 0.2f * a0;
    float a1 = A1 + adst; a1 = a1 > 0.f ? a1 : 0.2f * a1;
    float a2 = A2 + adst; a2 = a2 > 0.f ? a2 : 0.2f * a2;
    float a3 = A3 + adst; a3 = a3 > 0.f ? a3 : 0.2f * a3;
    float p0 = __expf(a0), p1 = __expf(a1), p2 = __expf(a2), p3 = __expf(a3);
    acc0 = fmaf(p0, bf2f_lo(u0), acc0); acc1 = fmaf(p0, bf2f_hi(u0), acc1);
    acc0 = fmaf(p1, bf2f_lo(u1), acc0); acc1 = fmaf(p1, bf2f_hi(u1), acc1);
    acc0 = fmaf(p2, bf2f_lo(u2), acc0); acc1 = fmaf(p2, bf2f_hi(u2), acc1);
    acc0 = fmaf(p3, bf2f_lo(u3), acc0); acc1 = fmaf(p3, bf2f_hi(u3), acc1);
    den += p0 + p1 + p2 + p3;
  }
  for (; e < e1; ++e) {
    int s = csr[e];
    float a = a_src[s * 8 + hd] + adst;
    a = a > 0.f ? a : 0.2f * a;
    float p = __expf(a);
    uint u = hu[(size_t)s * 64 + lane];
    acc0 = fmaf(p, bf2f_lo(u), acc0);
    acc1 = fmaf(p, bf2f_hi(u), acc1);
    den += p;
  }
  float r = 1.0f / (den + 1e-16f);
  float2 bv = ((const float2*)bias)[lane];
  float2 xv = ((const float2*)x)[(size_t)n * 64 + lane];
  float o0 = fmaf(acc0, r, bv.x + xv.x);
  float o1 = fmaf(acc1, r, bv.y + xv.y);

  float s1 = o0 + o1;
  float s2 = o0 * o0 + o1 * o1;
#pragma unroll
  for (int off = 32; off > 0; off >>= 1) {
    s1 += __shfl_xor(s1, off);
    s2 += __shfl_xor(s2, off);
  }
  float mean = s1 * (1.0f / 128.0f);
  float var = s2 * (1.0f / 128.0f) - mean * mean;
  var = var < 0.f ? 0.f : var;
  float rstd = rsqrtf(var + 1e-5f);
  float2 gv = ((const float2*)gamma)[lane];
  float2 bt = ((const float2*)beta)[lane];
  float2 ov;
  ov.x = (o0 - mean) * rstd * gv.x + bt.x;
  ov.y = (o1 - mean) * rstd * gv.y + bt.y;
  ((float2*)out)[(size_t)n * 64 + lane] = ov;
}

// ---------------- launch ----------------
extern "C" void kernel_launch(void* const* d_in, const int* in_sizes, int n_in,
                              void* d_out, int out_size, void* d_ws, size_t ws_size,
                              hipStream_t stream) {
  const float* x       = (const float*)d_in[0];
  const int*   ei      = (const int*)d_in[1];
  const float* W       = (const float*)d_in[2];
  const float* att_src = (const float*)d_in[3];
  const float* att_dst = (const float*)d_in[4];
  const float* bias    = (const float*)d_in[5];
  const float* gamma   = (const float*)d_in[6];
  const float* beta    = (const float*)d_in[7];
  float* out = (float*)d_out;

  char* ws = (char*)d_ws;
  ushort* hb   = (ushort*)(ws + OFF_HB);
  float* a_src = (float*)(ws + OFF_ASRC);
  float* a_dst = (float*)(ws + OFF_ADST);
  int* cnt  = (int*)(ws + OFF_CNT);
  int* offs = (int*)(ws + OFF_OFFS);
  int* run  = (int*)(ws + OFF_RUN);
  int* csr  = (int*)(ws + OFF_CSR);
  int* bsum = (int*)(ws + OFF_BSUM);
  char* Wt  = ws + OFF_WT;

  const int* srcIdx = ei;
  const int* dstIdx = ei + N_EDGES;

  k_prep<<<64, 256, 0, stream>>>(W, Wt);
  k_gemm2<<<(N_NODES + 63) / 64, 256, 0, stream>>>(x, Wt, hb, N_NODES);
  k_att<<<(N_NODES * 8 + 255) / 256, 256, 0, stream>>>(hb, att_src, att_dst, a_src, a_dst, N_NODES * 8);
  k_zero<<<(N_NODES + 255) / 256, 256, 0, stream>>>(cnt, N_NODES);
  k_count<<<1024, 256, 0, stream>>>(dstIdx, cnt, N_EDGES);
  k_scan1<<<SCAN_NB, SCAN_BLK, 0, stream>>>(cnt, offs, run, bsum, N_NODES);
  k_scan2<<<1, 64, 0, stream>>>(bsum, SCAN_NB);
  k_scan3<<<SCAN_NB, SCAN_BLK, 0, stream>>>(bsum, offs, run, N_NODES, SCAN_NB);
  k_scatter<<<1024, 256, 0, stream>>>(srcIdx, dstIdx, run, csr, N_EDGES);
  k_gat<<<(N_NODES + 3) / 4, 256, 0, stream>>>(hb, a_src, a_dst, offs, csr, x, bias, gamma, beta, out, N_NODES);
}

// Round 4
// 125.483 us; speedup vs baseline: 2.8697x; 1.3820x over previous
//
#include <hip/hip_runtime.h>

#define N_NODES 50000
#define N_EDGES 800000
#define D_FEAT 128
#define HEADS 8
#define HEAD_DIM 16
#define ELL_CAP 64

typedef __attribute__((ext_vector_type(8))) short bf16x8;
typedef __attribute__((ext_vector_type(4))) float f32x4;

static __device__ __forceinline__ ushort f2bf(float f) {
  uint u = __float_as_uint(f);
  u += 0x7fffu + ((u >> 16) & 1u);    // RNE
  return (ushort)(u >> 16);
}
static __device__ __forceinline__ float bf2f_lo(uint u) { return __uint_as_float(u << 16); }
static __device__ __forceinline__ float bf2f_hi(uint u) { return __uint_as_float(u & 0xffff0000u); }

static constexpr size_t alignup(size_t v) { return (v + 255) & ~255ull; }
// ---------------- workspace layout (bytes) ----------------
static constexpr size_t OFF_HB   = 0;                                           // [N,128] bf16
static constexpr size_t OFF_ASRC = alignup(OFF_HB + (size_t)N_NODES * 128 * 2); // [N,8] f32
static constexpr size_t OFF_ADST = alignup(OFF_ASRC + (size_t)N_NODES * 8 * 4); // [N,8] f32
static constexpr size_t OFF_CNT  = alignup(OFF_ADST + (size_t)N_NODES * 8 * 4); // [N] i32
static constexpr size_t OFF_OVFC = alignup(OFF_CNT + (size_t)N_NODES * 4);      // [1] i32
static constexpr size_t OFF_ELL  = alignup(OFF_OVFC + 4);                       // [N*64] u16
static constexpr size_t OFF_OVF  = alignup(OFF_ELL + (size_t)N_NODES * ELL_CAP * 2); // [E] int2
static constexpr size_t OFF_WT   = alignup(OFF_OVF + (size_t)N_EDGES * 8);      // [128*128] bf16 swizzled

// ---------------- prep: Wt bf16, transposed [n][k], XOR-swizzled ----------------
__global__ __launch_bounds__(256) void k_prep(const float* __restrict__ W,
                                              char* __restrict__ Wt) {
  int t = blockIdx.x * 256 + threadIdx.x;   // 0..16383
  int n = t >> 7, k = t & 127;
  int off = (n * 256 + k * 2) ^ ((n & 7) << 4);
  *(ushort*)(Wt + off) = f2bf(W[k * 128 + n]);
}

// ---------------- MFMA GEMM: h_bf16 = bf16(x) @ W ----------------
__global__ __launch_bounds__(256) void k_gemm2(const float* __restrict__ x,
                                               const char* __restrict__ Wt,
                                               ushort* __restrict__ hb, int N) {
  __shared__ ushort Wl[16384];              // 32KB, swizzled [n][k] bf16
  const int tid = threadIdx.x;
  const uint4* Wg4 = (const uint4*)Wt;
  uint4* Wl4 = (uint4*)Wl;
#pragma unroll
  for (int i = 0; i < 8; ++i) Wl4[tid + i * 256] = Wg4[tid + i * 256];
  __syncthreads();

  const int w = tid >> 6, l = tid & 63;
  const int R = blockIdx.x * 64 + w * 16;
  const int m = l & 15, kg = l >> 4;
  const char* Wlb = (const char*)Wl;

  f32x4 acc[8];
#pragma unroll
  for (int j = 0; j < 8; ++j) acc[j] = (f32x4){0.f, 0.f, 0.f, 0.f};

  const int row = R + m;
  const bool valid = row < N;
  const float4* xr = (const float4*)(x + (size_t)(valid ? row : 0) * 128);

#pragma unroll
  for (int kt = 0; kt < 4; ++kt) {
    const int k0 = kt * 32 + kg * 8;
    float4 xa = valid ? xr[k0 >> 2] : make_float4(0.f, 0.f, 0.f, 0.f);
    float4 xb = valid ? xr[(k0 >> 2) + 1] : make_float4(0.f, 0.f, 0.f, 0.f);
    bf16x8 a;
    a[0] = (short)f2bf(xa.x); a[1] = (short)f2bf(xa.y);
    a[2] = (short)f2bf(xa.z); a[3] = (short)f2bf(xa.w);
    a[4] = (short)f2bf(xb.x); a[5] = (short)f2bf(xb.y);
    a[6] = (short)f2bf(xb.z); a[7] = (short)f2bf(xb.w);
#pragma unroll
    for (int j = 0; j < 8; ++j) {
      int n = j * 16 + m;
      int off = (n * 256 + k0 * 2) ^ ((n & 7) << 4);
      bf16x8 b = *(const bf16x8*)(Wlb + off);
      acc[j] = __builtin_amdgcn_mfma_f32_16x16x32_bf16(a, b, acc[j], 0, 0, 0);
    }
  }
  // C layout: col = lane&15, row = (lane>>4)*4 + reg
#pragma unroll
  for (int j = 0; j < 8; ++j) {
    int col = j * 16 + m;
#pragma unroll
    for (int r = 0; r < 4; ++r) {
      int rr = R + kg * 4 + r;
      if (rr < N) hb[(size_t)rr * 128 + col] = f2bf(acc[j][r]);
    }
  }
}

// ---------------- per-(node,head) attention logits (bf16 h) ----------------
__global__ __launch_bounds__(256) void k_att(const ushort* __restrict__ hb,
                                             const float* __restrict__ att_src,
                                             const float* __restrict__ att_dst,
                                             float* __restrict__ a_src,
                                             float* __restrict__ a_dst, int NH) {
  int t = blockIdx.x * 256 + threadIdx.x;
  if (t >= NH) return;
  int hd = t & 7;
  const uint* hu = (const uint*)hb;
  float s = 0.f, d = 0.f;
#pragma unroll
  for (int i = 0; i < 8; ++i) {
    uint u = hu[(size_t)t * 8 + i];
    float f0 = bf2f_lo(u), f1 = bf2f_hi(u);
    s += f0 * att_src[hd * 16 + 2 * i] + f1 * att_src[hd * 16 + 2 * i + 1];
    d += f0 * att_dst[hd * 16 + 2 * i] + f1 * att_dst[hd * 16 + 2 * i + 1];
  }
  a_src[t] = s;
  a_dst[t] = d;
}

// ---------------- ELL build ----------------
__global__ void k_zero(int* __restrict__ cnt, int* __restrict__ ovfc, int n) {
  int t = blockIdx.x * blockDim.x + threadIdx.x;
  if (t < n) cnt[t] = 0;
  if (t == 0) *ovfc = 0;
}

// one quad of edges per thread: 4 independent atomics + 4 scattered ushort stores
__global__ __launch_bounds__(256) void k_scatter(const int* __restrict__ src,
                                                 const int* __restrict__ dst,
                                                 int* __restrict__ cnt,
                                                 ushort* __restrict__ ell,
                                                 int* __restrict__ ovfc,
                                                 int2* __restrict__ ovf, int E) {
  int t = blockIdx.x * 256 + threadIdx.x;
  int e = t * 4;
  if (e >= E) return;                       // E % 4 == 0: quad fully valid
  int4 d4 = *(const int4*)(dst + e);
  int4 s4 = *(const int4*)(src + e);
  int p0 = atomicAdd(&cnt[d4.x], 1);
  int p1 = atomicAdd(&cnt[d4.y], 1);
  int p2 = atomicAdd(&cnt[d4.z], 1);
  int p3 = atomicAdd(&cnt[d4.w], 1);
  if (p0 < ELL_CAP) ell[(size_t)d4.x * ELL_CAP + p0] = (ushort)s4.x;
  else { int q = atomicAdd(ovfc, 1); if (q < E) ovf[q] = make_int2(d4.x, s4.x); }
  if (p1 < ELL_CAP) ell[(size_t)d4.y * ELL_CAP + p1] = (ushort)s4.y;
  else { int q = atomicAdd(ovfc, 1); if (q < E) ovf[q] = make_int2(d4.y, s4.y); }
  if (p2 < ELL_CAP) ell[(size_t)d4.z * ELL_CAP + p2] = (ushort)s4.z;
  else { int q = atomicAdd(ovfc, 1); if (q < E) ovf[q] = make_int2(d4.z, s4.z); }
  if (p3 < ELL_CAP) ell[(size_t)d4.w * ELL_CAP + p3] = (ushort)s4.w;
  else { int q = atomicAdd(ovfc, 1); if (q < E) ovf[q] = make_int2(d4.w, s4.w); }
}

// ---------------- gather + softmax aggregate + residual + LN ----------------
// one wave per dst node; lane owns features {2*lane, 2*lane+1}; head = lane>>3.
// alpha normalization factors out: out = (sum p*h)/(sum p).
__global__ __launch_bounds__(256) void k_gat(const ushort* __restrict__ hb,
                                             const float* __restrict__ a_src,
                                             const float* __restrict__ a_dst,
                                             const int* __restrict__ cnt,
                                             const ushort* __restrict__ ell,
                                             const int* __restrict__ ovfc,
                                             const int2* __restrict__ ovf,
                                             const float* __restrict__ x,
                                             const float* __restrict__ bias,
                                             const float* __restrict__ gamma,
                                             const float* __restrict__ beta,
                                             float* __restrict__ out, int N) {
  const int wid = threadIdx.x >> 6;
  const int lane = threadIdx.x & 63;
  const int n = blockIdx.x * 4 + wid;
  if (n >= N) return;
  const int hd = lane >> 3;
  const float adst = a_dst[n * 8 + hd];
  const int degt = cnt[n];
  const int deg = degt < ELL_CAP ? degt : ELL_CAP;
  const uint* hu = (const uint*)hb;
  const ushort* row = ell + (size_t)n * ELL_CAP;

  float acc0 = 0.f, acc1 = 0.f, den = 0.f;
  int e = 0;
  for (; e + 4 <= deg; e += 4) {
    ushort4 q = *(const ushort4*)(row + e);
    int s0 = q.x, s1 = q.y, s2 = q.z, s3 = q.w;
    float A0 = a_src[s0 * 8 + hd], A1 = a_src[s1 * 8 + hd];
    float A2 = a_src[s2 * 8 + hd], A3 = a_src[s3 * 8 + hd];
    uint u0 = hu[(size_t)s0 * 64 + lane], u1 = hu[(size_t)s1 * 64 + lane];
    uint u2 = hu[(size_t)s2 * 64 + lane], u3 = hu[(size_t)s3 * 64 + lane];
    float a0 = A0 + adst; a0 = a0 > 0.f ? a0 : 0.2f * a0;
    float a1 = A1 + adst; a1 = a1 > 0.f ? a1 : 0.2f * a1;
    float a2 = A2 + adst; a2 = a2 > 0.f ? a2 : 0.2f * a2;
    float a3 = A3 + adst; a3 = a3 > 0.f ? a3 : 0.2f * a3;
    float p0 = __expf(a0), p1 = __expf(a1), p2 = __expf(a2), p3 = __expf(a3);
    acc0 = fmaf(p0, bf2f_lo(u0), acc0); acc1 = fmaf(p0, bf2f_hi(u0), acc1);
    acc0 = fmaf(p1, bf2f_lo(u1), acc0); acc1 = fmaf(p1, bf2f_hi(u1), acc1);
    acc0 = fmaf(p2, bf2f_lo(u2), acc0); acc1 = fmaf(p2, bf2f_hi(u2), acc1);
    acc0 = fmaf(p3, bf2f_lo(u3), acc0); acc1 = fmaf(p3, bf2f_hi(u3), acc1);
    den += p0 + p1 + p2 + p3;
  }
  for (; e < deg; ++e) {
    int s = row[e];
    float a = a_src[s * 8 + hd] + adst;
    a = a > 0.f ? a : 0.2f * a;
    float p = __expf(a);
    uint u = hu[(size_t)s * 64 + lane];
    acc0 = fmaf(p, bf2f_lo(u), acc0);
    acc1 = fmaf(p, bf2f_hi(u), acc1);
    den += p;
  }
  if (degt > ELL_CAP) {                     // overflow path (statistically unreachable)
    int novf = *ovfc;
    for (int q = 0; q < novf; ++q) {
      int2 pr = ovf[q];
      if (pr.x == n) {
        int s = pr.y;
        float a = a_src[s * 8 + hd] + adst;
        a = a > 0.f ? a : 0.2f * a;
        float p = __expf(a);
        uint u = hu[(size_t)s * 64 + lane];
        acc0 = fmaf(p, bf2f_lo(u), acc0);
        acc1 = fmaf(p, bf2f_hi(u), acc1);
        den += p;
      }
    }
  }
  float r = 1.0f / (den + 1e-16f);
  float2 bv = ((const float2*)bias)[lane];
  float2 xv = ((const float2*)x)[(size_t)n * 64 + lane];
  float o0 = fmaf(acc0, r, bv.x + xv.x);
  float o1 = fmaf(acc1, r, bv.y + xv.y);

  float s1 = o0 + o1;
  float s2 = o0 * o0 + o1 * o1;
#pragma unroll
  for (int off = 32; off > 0; off >>= 1) {
    s1 += __shfl_xor(s1, off);
    s2 += __shfl_xor(s2, off);
  }
  float mean = s1 * (1.0f / 128.0f);
  float var = s2 * (1.0f / 128.0f) - mean * mean;
  var = var < 0.f ? 0.f : var;
  float rstd = rsqrtf(var + 1e-5f);
  float2 gv = ((const float2*)gamma)[lane];
  float2 bt = ((const float2*)beta)[lane];
  float2 ov;
  ov.x = (o0 - mean) * rstd * gv.x + bt.x;
  ov.y = (o1 - mean) * rstd * gv.y + bt.y;
  ((float2*)out)[(size_t)n * 64 + lane] = ov;
}

// ---------------- launch ----------------
extern "C" void kernel_launch(void* const* d_in, const int* in_sizes, int n_in,
                              void* d_out, int out_size, void* d_ws, size_t ws_size,
                              hipStream_t stream) {
  const float* x       = (const float*)d_in[0];
  const int*   ei      = (const int*)d_in[1];
  const float* W       = (const float*)d_in[2];
  const float* att_src = (const float*)d_in[3];
  const float* att_dst = (const float*)d_in[4];
  const float* bias    = (const float*)d_in[5];
  const float* gamma   = (const float*)d_in[6];
  const float* beta    = (const float*)d_in[7];
  float* out = (float*)d_out;

  char* ws = (char*)d_ws;
  ushort* hb   = (ushort*)(ws + OFF_HB);
  float* a_src = (float*)(ws + OFF_ASRC);
  float* a_dst = (float*)(ws + OFF_ADST);
  int* cnt   = (int*)(ws + OFF_CNT);
  int* ovfc  = (int*)(ws + OFF_OVFC);
  ushort* ell = (ushort*)(ws + OFF_ELL);
  int2* ovf  = (int2*)(ws + OFF_OVF);
  char* Wt   = ws + OFF_WT;

  const int* srcIdx = ei;
  const int* dstIdx = ei + N_EDGES;

  k_zero<<<(N_NODES + 255) / 256, 256, 0, stream>>>(cnt, ovfc, N_NODES);
  k_scatter<<<(N_EDGES / 4 + 255) / 256, 256, 0, stream>>>(srcIdx, dstIdx, cnt, ell, ovfc, ovf, N_EDGES);
  k_prep<<<64, 256, 0, stream>>>(W, Wt);
  k_gemm2<<<(N_NODES + 63) / 64, 256, 0, stream>>>(x, Wt, hb, N_NODES);
  k_att<<<(N_NODES * 8 + 255) / 256, 256, 0, stream>>>(hb, att_src, att_dst, a_src, a_dst, N_NODES * 8);
  k_gat<<<(N_NODES + 3) / 4, 256, 0, stream>>>(hb, a_src, a_dst, cnt, ell, ovfc, ovf, x, bias, gamma, beta, out, N_NODES);
}

// Round 5
// 93.126 us; speedup vs baseline: 3.8667x; 1.3475x over previous
//
#include <hip/hip_runtime.h>

#define N_NODES 50000
#define N_EDGES 800000
#define D_FEAT 128
#define HEADS 8
#define HEAD_DIM 16
#define ELL_CAP 64
#define NBKT 196            // dst>>8 in [0,196)
#define BKT_CAP 5120        // mean 4096, sigma ~64 -> +16 sigma
#define OVF_CAP 65536

typedef __attribute__((ext_vector_type(8))) short bf16x8;
typedef __attribute__((ext_vector_type(4))) float f32x4;

static __device__ __forceinline__ ushort f2bf(float f) {
  uint u = __float_as_uint(f);
  u += 0x7fffu + ((u >> 16) & 1u);    // RNE
  return (ushort)(u >> 16);
}
static __device__ __forceinline__ float bf2f_lo(uint u) { return __uint_as_float(u << 16); }
static __device__ __forceinline__ float bf2f_hi(uint u) { return __uint_as_float(u & 0xffff0000u); }

static constexpr size_t alignup(size_t v) { return (v + 255) & ~255ull; }
// ---------------- workspace layout (bytes) ----------------
static constexpr size_t OFF_HB   = 0;                                           // [N,128] bf16
static constexpr size_t OFF_ASRC = alignup(OFF_HB + (size_t)N_NODES * 128 * 2); // [N,8] f32
static constexpr size_t OFF_ADST = alignup(OFF_ASRC + (size_t)N_NODES * 8 * 4); // [N,8] f32
static constexpr size_t OFF_CNT  = alignup(OFF_ADST + (size_t)N_NODES * 8 * 4); // [N] i32
static constexpr size_t OFF_GCNT = alignup(OFF_CNT + (size_t)N_NODES * 4);      // [NBKT] i32
static constexpr size_t OFF_OVFC = alignup(OFF_GCNT + (size_t)NBKT * 4);        // [1] i32
static constexpr size_t OFF_ELL  = alignup(OFF_OVFC + 4);                       // [N*64] u16
static constexpr size_t OFF_BKT  = alignup(OFF_ELL + (size_t)N_NODES * ELL_CAP * 2); // [NBKT*BKT_CAP] u32
static constexpr size_t OFF_OVF  = alignup(OFF_BKT + (size_t)NBKT * BKT_CAP * 4);    // [OVF_CAP] int2
static constexpr size_t OFF_WT   = alignup(OFF_OVF + (size_t)OVF_CAP * 8);      // [128*128] bf16 swizzled

// ---------------- prep: Wt bf16, transposed [n][k], XOR-swizzled ----------------
__global__ __launch_bounds__(256) void k_prep(const float* __restrict__ W,
                                              char* __restrict__ Wt) {
  int t = blockIdx.x * 256 + threadIdx.x;   // 0..16383
  int n = t >> 7, k = t & 127;
  int off = (n * 256 + k * 2) ^ ((n & 7) << 4);
  *(ushort*)(Wt + off) = f2bf(W[k * 128 + n]);
}

// ---------------- MFMA GEMM: h_bf16 = bf16(x) @ W ----------------
__global__ __launch_bounds__(256) void k_gemm2(const float* __restrict__ x,
                                               const char* __restrict__ Wt,
                                               ushort* __restrict__ hb, int N) {
  __shared__ ushort Wl[16384];              // 32KB, swizzled [n][k] bf16
  const int tid = threadIdx.x;
  const uint4* Wg4 = (const uint4*)Wt;
  uint4* Wl4 = (uint4*)Wl;
#pragma unroll
  for (int i = 0; i < 8; ++i) Wl4[tid + i * 256] = Wg4[tid + i * 256];
  __syncthreads();

  const int w = tid >> 6, l = tid & 63;
  const int R = blockIdx.x * 64 + w * 16;
  const int m = l & 15, kg = l >> 4;
  const char* Wlb = (const char*)Wl;

  f32x4 acc[8];
#pragma unroll
  for (int j = 0; j < 8; ++j) acc[j] = (f32x4){0.f, 0.f, 0.f, 0.f};

  const int row = R + m;
  const bool valid = row < N;
  const float4* xr = (const float4*)(x + (size_t)(valid ? row : 0) * 128);

#pragma unroll
  for (int kt = 0; kt < 4; ++kt) {
    const int k0 = kt * 32 + kg * 8;
    float4 xa = valid ? xr[k0 >> 2] : make_float4(0.f, 0.f, 0.f, 0.f);
    float4 xb = valid ? xr[(k0 >> 2) + 1] : make_float4(0.f, 0.f, 0.f, 0.f);
    bf16x8 a;
    a[0] = (short)f2bf(xa.x); a[1] = (short)f2bf(xa.y);
    a[2] = (short)f2bf(xa.z); a[3] = (short)f2bf(xa.w);
    a[4] = (short)f2bf(xb.x); a[5] = (short)f2bf(xb.y);
    a[6] = (short)f2bf(xb.z); a[7] = (short)f2bf(xb.w);
#pragma unroll
    for (int j = 0; j < 8; ++j) {
      int n = j * 16 + m;
      int off = (n * 256 + k0 * 2) ^ ((n & 7) << 4);
      bf16x8 b = *(const bf16x8*)(Wlb + off);
      acc[j] = __builtin_amdgcn_mfma_f32_16x16x32_bf16(a, b, acc[j], 0, 0, 0);
    }
  }
  // C layout: col = lane&15, row = (lane>>4)*4 + reg
#pragma unroll
  for (int j = 0; j < 8; ++j) {
    int col = j * 16 + m;
#pragma unroll
    for (int r = 0; r < 4; ++r) {
      int rr = R + kg * 4 + r;
      if (rr < N) hb[(size_t)rr * 128 + col] = f2bf(acc[j][r]);
    }
  }
}

// ---------------- per-(node,head) attention logits (bf16 h) ----------------
__global__ __launch_bounds__(256) void k_att(const ushort* __restrict__ hb,
                                             const float* __restrict__ att_src,
                                             const float* __restrict__ att_dst,
                                             float* __restrict__ a_src,
                                             float* __restrict__ a_dst, int NH) {
  int t = blockIdx.x * 256 + threadIdx.x;
  if (t >= NH) return;
  int hd = t & 7;
  const uint* hu = (const uint*)hb;
  float s = 0.f, d = 0.f;
#pragma unroll
  for (int i = 0; i < 8; ++i) {
    uint u = hu[(size_t)t * 8 + i];
    float f0 = bf2f_lo(u), f1 = bf2f_hi(u);
    s += f0 * att_src[hd * 16 + 2 * i] + f1 * att_src[hd * 16 + 2 * i + 1];
    d += f0 * att_dst[hd * 16 + 2 * i] + f1 * att_dst[hd * 16 + 2 * i + 1];
  }
  a_src[t] = s;
  a_dst[t] = d;
}

// ---------------- tiny init: bucket counters + overflow counter ----------------
__global__ void k_zero0(int* __restrict__ gcnt, int* __restrict__ ovfc) {
  int t = threadIdx.x;
  if (t < NBKT) gcnt[t] = 0;
  if (t == 0) *ovfc = 0;
}

// ---------------- pass 1: bin edges into 196 coarse buckets ----------------
// block = 256 thr, 4096 edges. LDS histogram -> 1 global atomic per bucket ->
// contiguous chunk writes (~84B runs) into bkt[b*BKT_CAP ...].
__global__ __launch_bounds__(256) void k_bin(const int* __restrict__ src,
                                             const int* __restrict__ dst,
                                             int* __restrict__ gcnt,
                                             uint* __restrict__ bkt,
                                             int* __restrict__ ovfc,
                                             int2* __restrict__ ovf, int E) {
  __shared__ int hist[NBKT];
  __shared__ int base[NBKT];
  const int t = threadIdx.x;
  const int e0 = blockIdx.x * 4096;
  for (int i = t; i < NBKT; i += 256) hist[i] = 0;
  __syncthreads();

  uint pk[16];
  int bk[16];
#pragma unroll
  for (int j = 0; j < 4; ++j) {
    int e = e0 + j * 1024 + t * 4;
    if (e < E) {                       // E%4==0: quad fully valid
      int4 d4 = *(const int4*)(dst + e);
      int4 s4 = *(const int4*)(src + e);
      bk[j * 4 + 0] = d4.x >> 8; pk[j * 4 + 0] = ((uint)(d4.x & 255) << 16) | (uint)s4.x;
      bk[j * 4 + 1] = d4.y >> 8; pk[j * 4 + 1] = ((uint)(d4.y & 255) << 16) | (uint)s4.y;
      bk[j * 4 + 2] = d4.z >> 8; pk[j * 4 + 2] = ((uint)(d4.z & 255) << 16) | (uint)s4.z;
      bk[j * 4 + 3] = d4.w >> 8; pk[j * 4 + 3] = ((uint)(d4.w & 255) << 16) | (uint)s4.w;
      atomicAdd(&hist[bk[j * 4 + 0]], 1);
      atomicAdd(&hist[bk[j * 4 + 1]], 1);
      atomicAdd(&hist[bk[j * 4 + 2]], 1);
      atomicAdd(&hist[bk[j * 4 + 3]], 1);
    } else {
      bk[j * 4 + 0] = -1; bk[j * 4 + 1] = -1; bk[j * 4 + 2] = -1; bk[j * 4 + 3] = -1;
      pk[j * 4 + 0] = 0;  pk[j * 4 + 1] = 0;  pk[j * 4 + 2] = 0;  pk[j * 4 + 3] = 0;
    }
  }
  __syncthreads();
  for (int i = t; i < NBKT; i += 256) {
    base[i] = atomicAdd(&gcnt[i], hist[i]);
    hist[i] = 0;
  }
  __syncthreads();
#pragma unroll
  for (int j = 0; j < 16; ++j) {
    if (bk[j] >= 0) {
      int pos = atomicAdd(&hist[bk[j]], 1);
      int gp = base[bk[j]] + pos;
      if (gp < BKT_CAP) {
        bkt[(size_t)bk[j] * BKT_CAP + gp] = pk[j];
      } else {
        int q = atomicAdd(ovfc, 1);
        if (q < OVF_CAP) ovf[q] = make_int2((bk[j] << 8) | (int)(pk[j] >> 16), (int)(pk[j] & 0xffffu));
      }
    }
  }
}

// ---------------- pass 2: per-bucket ELL build in LDS, coalesced writeout ----
__global__ __launch_bounds__(256) void k_build(const uint* __restrict__ bkt,
                                               const int* __restrict__ gcnt,
                                               int* __restrict__ cnt,
                                               ushort* __restrict__ ell,
                                               int* __restrict__ ovfc,
                                               int2* __restrict__ ovf) {
  __shared__ ushort lell[256 * ELL_CAP];   // 32KB
  __shared__ int lcnt[256];
  const int b = blockIdx.x;
  const int t = threadIdx.x;
  lcnt[t] = 0;
  __syncthreads();

  const int nb = min(gcnt[b], BKT_CAP);
  for (int i = t; i < nb; i += 256) {
    uint pk = bkt[(size_t)b * BKT_CAP + i];
    int dl = (int)(pk >> 16);
    int pos = atomicAdd(&lcnt[dl], 1);
    if (pos < ELL_CAP) {
      lell[dl * ELL_CAP + pos] = (ushort)(pk & 0xffffu);
    } else {
      int q = atomicAdd(ovfc, 1);
      if (q < OVF_CAP) ovf[q] = make_int2((b << 8) | dl, (int)(pk & 0xffffu));
    }
  }
  __syncthreads();

  const int n0 = b << 8;
  if (n0 + t < N_NODES) cnt[n0 + t] = lcnt[t];
  const uint4* l4 = (const uint4*)lell;
  uint4* g4 = (uint4*)(ell + (size_t)n0 * ELL_CAP);
  for (int i = t; i < 2048; i += 256) {       // 256 nodes * 128B = 32KB
    if (n0 + (i >> 3) < N_NODES) g4[i] = l4[i];
  }
}

// ---------------- gather + softmax aggregate + residual + LN ----------------
// one wave per dst node; lane owns features {2*lane, 2*lane+1}; head = lane>>3.
// alpha normalization factors out: out = (sum p*h)/(sum p).
__global__ __launch_bounds__(256) void k_gat(const ushort* __restrict__ hb,
                                             const float* __restrict__ a_src,
                                             const float* __restrict__ a_dst,
                                             const int* __restrict__ cnt,
                                             const ushort* __restrict__ ell,
                                             const int* __restrict__ ovfc,
                                             const int2* __restrict__ ovf,
                                             const float* __restrict__ x,
                                             const float* __restrict__ bias,
                                             const float* __restrict__ gamma,
                                             const float* __restrict__ beta,
                                             float* __restrict__ out, int N) {
  const int wid = threadIdx.x >> 6;
  const int lane = threadIdx.x & 63;
  const int n = blockIdx.x * 4 + wid;
  if (n >= N) return;
  const int hd = lane >> 3;
  const float adst = a_dst[n * 8 + hd];
  const int degt = cnt[n];
  const int deg = degt < ELL_CAP ? degt : ELL_CAP;
  const uint* hu = (const uint*)hb;
  const ushort* row = ell + (size_t)n * ELL_CAP;

  float acc0 = 0.f, acc1 = 0.f, den = 0.f;
  int e = 0;
  for (; e + 4 <= deg; e += 4) {
    ushort4 q = *(const ushort4*)(row + e);
    int s0 = q.x, s1 = q.y, s2 = q.z, s3 = q.w;
    float A0 = a_src[s0 * 8 + hd], A1 = a_src[s1 * 8 + hd];
    float A2 = a_src[s2 * 8 + hd], A3 = a_src[s3 * 8 + hd];
    uint u0 = hu[(size_t)s0 * 64 + lane], u1 = hu[(size_t)s1 * 64 + lane];
    uint u2 = hu[(size_t)s2 * 64 + lane], u3 = hu[(size_t)s3 * 64 + lane];
    float a0 = A0 + adst; a0 = a0 > 0.f ? a0 : 0.2f * a0;
    float a1 = A1 + adst; a1 = a1 > 0.f ? a1 : 0.2f * a1;
    float a2 = A2 + adst; a2 = a2 > 0.f ? a2 : 0.2f * a2;
    float a3 = A3 + adst; a3 = a3 > 0.f ? a3 : 0.2f * a3;
    float p0 = __expf(a0), p1 = __expf(a1), p2 = __expf(a2), p3 = __expf(a3);
    acc0 = fmaf(p0, bf2f_lo(u0), acc0); acc1 = fmaf(p0, bf2f_hi(u0), acc1);
    acc0 = fmaf(p1, bf2f_lo(u1), acc0); acc1 = fmaf(p1, bf2f_hi(u1), acc1);
    acc0 = fmaf(p2, bf2f_lo(u2), acc0); acc1 = fmaf(p2, bf2f_hi(u2), acc1);
    acc0 = fmaf(p3, bf2f_lo(u3), acc0); acc1 = fmaf(p3, bf2f_hi(u3), acc1);
    den += p0 + p1 + p2 + p3;
  }
  for (; e < deg; ++e) {
    int s = row[e];
    float a = a_src[s * 8 + hd] + adst;
    a = a > 0.f ? a : 0.2f * a;
    float p = __expf(a);
    uint u = hu[(size_t)s * 64 + lane];
    acc0 = fmaf(p, bf2f_lo(u), acc0);
    acc1 = fmaf(p, bf2f_hi(u), acc1);
    den += p;
  }
  {
    int novf = *ovfc;                        // ~always 0; one broadcast load
    if (novf > 0) {
      novf = novf < OVF_CAP ? novf : OVF_CAP;
      for (int q = 0; q < novf; ++q) {
        int2 pr = ovf[q];
        if (pr.x == n) {
          int s = pr.y;
          float a = a_src[s * 8 + hd] + adst;
          a = a > 0.f ? a : 0.2f * a;
          float p = __expf(a);
          uint u = hu[(size_t)s * 64 + lane];
          acc0 = fmaf(p, bf2f_lo(u), acc0);
          acc1 = fmaf(p, bf2f_hi(u), acc1);
          den += p;
        }
      }
    }
  }
  float r = 1.0f / (den + 1e-16f);
  float2 bv = ((const float2*)bias)[lane];
  float2 xv = ((const float2*)x)[(size_t)n * 64 + lane];
  float o0 = fmaf(acc0, r, bv.x + xv.x);
  float o1 = fmaf(acc1, r, bv.y + xv.y);

  float s1 = o0 + o1;
  float s2 = o0 * o0 + o1 * o1;
#pragma unroll
  for (int off = 32; off > 0; off >>= 1) {
    s1 += __shfl_xor(s1, off);
    s2 += __shfl_xor(s2, off);
  }
  float mean = s1 * (1.0f / 128.0f);
  float var = s2 * (1.0f / 128.0f) - mean * mean;
  var = var < 0.f ? 0.f : var;
  float rstd = rsqrtf(var + 1e-5f);
  float2 gv = ((const float2*)gamma)[lane];
  float2 bt = ((const float2*)beta)[lane];
  float2 ov;
  ov.x = (o0 - mean) * rstd * gv.x + bt.x;
  ov.y = (o1 - mean) * rstd * gv.y + bt.y;
  ((float2*)out)[(size_t)n * 64 + lane] = ov;
}

// ---------------- launch ----------------
extern "C" void kernel_launch(void* const* d_in, const int* in_sizes, int n_in,
                              void* d_out, int out_size, void* d_ws, size_t ws_size,
                              hipStream_t stream) {
  const float* x       = (const float*)d_in[0];
  const int*   ei      = (const int*)d_in[1];
  const float* W       = (const float*)d_in[2];
  const float* att_src = (const float*)d_in[3];
  const float* att_dst = (const float*)d_in[4];
  const float* bias    = (const float*)d_in[5];
  const float* gamma   = (const float*)d_in[6];
  const float* beta    = (const float*)d_in[7];
  float* out = (float*)d_out;

  char* ws = (char*)d_ws;
  ushort* hb   = (ushort*)(ws + OFF_HB);
  float* a_src = (float*)(ws + OFF_ASRC);
  float* a_dst = (float*)(ws + OFF_ADST);
  int* cnt   = (int*)(ws + OFF_CNT);
  int* gcnt  = (int*)(ws + OFF_GCNT);
  int* ovfc  = (int*)(ws + OFF_OVFC);
  ushort* ell = (ushort*)(ws + OFF_ELL);
  uint* bkt  = (uint*)(ws + OFF_BKT);
  int2* ovf  = (int2*)(ws + OFF_OVF);
  char* Wt   = ws + OFF_WT;

  const int* srcIdx = ei;
  const int* dstIdx = ei + N_EDGES;

  k_zero0<<<1, 256, 0, stream>>>(gcnt, ovfc);
  k_bin<<<(N_EDGES + 4095) / 4096, 256, 0, stream>>>(srcIdx, dstIdx, gcnt, bkt, ovfc, ovf, N_EDGES);
  k_build<<<NBKT, 256, 0, stream>>>(bkt, gcnt, cnt, ell, ovfc, ovf);
  k_prep<<<64, 256, 0, stream>>>(W, Wt);
  k_gemm2<<<(N_NODES + 63) / 64, 256, 0, stream>>>(x, Wt, hb, N_NODES);
  k_att<<<(N_NODES * 8 + 255) / 256, 256, 0, stream>>>(hb, att_src, att_dst, a_src, a_dst, N_NODES * 8);
  k_gat<<<(N_NODES + 3) / 4, 256, 0, stream>>>(hb, a_src, a_dst, cnt, ell, ovfc, ovf, x, bias, gamma, beta, out, N_NODES);
}